// Round 4
// baseline (458.059 us; speedup 1.0000x reference)
//
#include <hip/hip_runtime.h>

#define N_NODES 100000
#define N_EDGES 1600000
#define IN_F 128
#define H_F 64
#define C_F 16

#define SCAN_NB 391  // ceil(100000/256)

typedef __attribute__((ext_vector_type(8))) short bf16x8;  // 8 bf16 (4 VGPRs)
typedef __attribute__((ext_vector_type(4))) float f32x4;   // MFMA C/D

// fp32 -> bf16 round-to-nearest-even (inputs are finite; no NaN handling)
__device__ inline short f2bf(float f) {
  unsigned u = __float_as_uint(f);
  unsigned r = (u + 0x7fff + ((u >> 16) & 1)) >> 16;
  return (short)r;
}

// ---------------- GEMM1 (MFMA): H1 = X @ W1  (100000 x 128 @ 128 x 64) ----
// One wave computes a 16(node) x 64(feat) tile: 4 col-tiles x 4 k-steps of
// mfma_f32_16x16x32_bf16. B (=W1) fragments pre-swizzled in LDS so each B
// load is one dense ds_read_b128. A: lane reads 32B of its X row, coalesced.
__global__ __launch_bounds__(256) void gemm1_mfma_kernel(
    const float* __restrict__ X, const float* __restrict__ W1,
    float* __restrict__ H1) {
  __shared__ short ldsB[16 * 512];  // 16 frags x (64 lanes x 8 bf16) = 16 KB
  for (int idx = threadIdx.x; idx < 16 * 512; idx += 256) {
    int frag = idx >> 9;    // c*4 + s
    int entry = idx & 511;  // lane*8 + j
    int lane = entry >> 3, j = entry & 7;
    int c = frag >> 2, s = frag & 3;
    int k = s * 32 + (lane >> 4) * 8 + j;
    int n = c * 16 + (lane & 15);
    ldsB[idx] = f2bf(W1[k * H_F + n]);
  }
  __syncthreads();

  int wave = threadIdx.x >> 6;
  int lane = threadIdx.x & 63;
  int rt = blockIdx.x * 4 + wave;  // row (node) tile, 16 nodes each
  if (rt >= N_NODES / 16) return;  // 6250 tiles exactly
  int node0 = rt * 16;
  int l = lane & 15, q = lane >> 4;

  const float* xp = X + (size_t)(node0 + l) * IN_F + q * 8;
  f32x4 acc[4] = {f32x4{0.f, 0.f, 0.f, 0.f}, f32x4{0.f, 0.f, 0.f, 0.f},
                  f32x4{0.f, 0.f, 0.f, 0.f}, f32x4{0.f, 0.f, 0.f, 0.f}};
#pragma unroll
  for (int s = 0; s < 4; ++s) {
    float4 x0 = *(const float4*)(xp + s * 32);
    float4 x1 = *(const float4*)(xp + s * 32 + 4);
    bf16x8 a;
    a[0] = f2bf(x0.x); a[1] = f2bf(x0.y); a[2] = f2bf(x0.z); a[3] = f2bf(x0.w);
    a[4] = f2bf(x1.x); a[5] = f2bf(x1.y); a[6] = f2bf(x1.z); a[7] = f2bf(x1.w);
#pragma unroll
    for (int c = 0; c < 4; ++c) {
      bf16x8 b = *(const bf16x8*)&ldsB[(c * 4 + s) * 512 + lane * 8];
      acc[c] = __builtin_amdgcn_mfma_f32_16x16x32_bf16(a, b, acc[c], 0, 0, 0);
    }
  }
  // C/D: col = lane&15 (feat offset), row = q*4 + reg (node offset)
#pragma unroll
  for (int c = 0; c < 4; ++c)
#pragma unroll
    for (int r = 0; r < 4; ++r)
      H1[(size_t)(node0 + q * 4 + r) * H_F + c * 16 + l] = acc[c][r];
}

// ---------------- CSR build ----------------
__global__ __launch_bounds__(256) void zero_deg_kernel(int* __restrict__ deg) {
  int i = blockIdx.x * 256 + threadIdx.x;
  if (i < N_NODES) deg[i] = 0;
}

__global__ __launch_bounds__(256) void hist_kernel(
    const int* __restrict__ dst, int* __restrict__ deg) {
  int e = blockIdx.x * 256 + threadIdx.x;
  if (e < N_EDGES) atomicAdd(&deg[dst[e]], 1);
}

__global__ __launch_bounds__(256) void scan_a_kernel(
    const int* __restrict__ deg, int* __restrict__ offs,
    int* __restrict__ blockSums) {
  __shared__ int s[256];
  int i = blockIdx.x * 256 + threadIdx.x;
  int v = (i < N_NODES) ? deg[i] : 0;
  s[threadIdx.x] = v;
  __syncthreads();
#pragma unroll
  for (int d = 1; d < 256; d <<= 1) {
    int t = (threadIdx.x >= d) ? s[threadIdx.x - d] : 0;
    __syncthreads();
    s[threadIdx.x] += t;
    __syncthreads();
  }
  if (i < N_NODES) offs[i] = s[threadIdx.x] - v;  // exclusive
  if (threadIdx.x == 255) blockSums[blockIdx.x] = s[255];
}

__global__ __launch_bounds__(512) void scan_b_kernel(
    const int* __restrict__ blockSums, int* __restrict__ blockOffs,
    int* __restrict__ offs) {
  __shared__ int s[512];
  int v = (threadIdx.x < SCAN_NB) ? blockSums[threadIdx.x] : 0;
  s[threadIdx.x] = v;
  __syncthreads();
#pragma unroll
  for (int d = 1; d < 512; d <<= 1) {
    int t = (threadIdx.x >= d) ? s[threadIdx.x - d] : 0;
    __syncthreads();
    s[threadIdx.x] += t;
    __syncthreads();
  }
  if (threadIdx.x < SCAN_NB) blockOffs[threadIdx.x] = s[threadIdx.x] - v;
  if (threadIdx.x == 0) offs[N_NODES] = N_EDGES;
}

__global__ __launch_bounds__(256) void scan_c_kernel(
    int* __restrict__ offs, const int* __restrict__ blockOffs,
    int* __restrict__ cursor) {
  int i = blockIdx.x * 256 + threadIdx.x;
  if (i < N_NODES) {
    int o = offs[i] + blockOffs[blockIdx.x];
    offs[i] = o;
    cursor[i] = o;
  }
}

// bucket edges by dst: one packed 8B record per edge -> single dwordx2 store
__global__ __launch_bounds__(256) void fill_kernel(
    const int* __restrict__ src, const int* __restrict__ dst,
    const float* __restrict__ ew, int* __restrict__ cursor,
    int2* __restrict__ epk) {
  int e = blockIdx.x * 256 + threadIdx.x;
  if (e >= N_EDGES) return;
  int d = dst[e];
  int s = src[e];
  float w = ew[e];
  int pos = atomicAdd(&cursor[d], 1);
  epk[pos] = make_int2(s, __float_as_int(w));
}

// ---------------- Gather1: agg[n,f] = b1[f] + sum_in w_e * H1[src,f] ------
// One wave per node (64 lanes = 64 feats). Packed edge records: 1 dwordx2.
__global__ __launch_bounds__(256) void gather1_kernel(
    const float* __restrict__ H1, const int* __restrict__ offs,
    const int2* __restrict__ epk, const float* __restrict__ b1,
    float* __restrict__ agg) {
  int t = blockIdx.x * 256 + threadIdx.x;
  int n = t >> 6;
  if (n >= N_NODES) return;
  int f = t & 63;
  int beg = offs[n];
  int end = offs[n + 1];
  float acc0 = b1[f];
  float acc1 = 0.f;
  int i = beg;
  for (; i + 1 < end; i += 2) {
    int2 e0 = epk[i], e1 = epk[i + 1];
    acc0 += H1[e0.x * H_F + f] * __int_as_float(e0.y);
    acc1 += H1[e1.x * H_F + f] * __int_as_float(e1.y);
  }
  if (i < end) {
    int2 e0 = epk[i];
    acc0 += H1[e0.x * H_F + f] * __int_as_float(e0.y);
  }
  agg[n * H_F + f] = acc0 + acc1;
}

// ---------------- GEMM2: H2 = relu(agg1) @ W2  (N x 64 @ 64 x 16) ---------
__global__ __launch_bounds__(256) void gemm2_kernel(
    const float* __restrict__ agg1, const float* __restrict__ W2,
    float* __restrict__ H2) {
  __shared__ float w[H_F * C_F];
  for (int i = threadIdx.x; i < H_F * C_F; i += 256) w[i] = W2[i];
  __syncthreads();
  int idx = blockIdx.x * 256 + threadIdx.x;
  if (idx >= N_NODES * C_F) return;
  int n = idx >> 4;
  int f = idx & 15;
  const float* hr = agg1 + n * H_F;
  float acc = 0.f;
#pragma unroll
  for (int k = 0; k < H_F; ++k) {
    float h = hr[k];
    h = h > 0.f ? h : 0.f;
    acc += h * w[k * C_F + f];
  }
  H2[idx] = acc;
}

// ---------------- Gather2: out[n,f] = b2[f] + sum_in w_e * H2[src,f] ------
__global__ __launch_bounds__(256) void gather2_kernel(
    const float* __restrict__ H2, const int* __restrict__ offs,
    const int2* __restrict__ epk, const float* __restrict__ b2,
    float* __restrict__ out) {
  int t = blockIdx.x * 256 + threadIdx.x;
  int n = t >> 4;
  if (n >= N_NODES) return;
  int f = t & 15;
  int beg = offs[n];
  int end = offs[n + 1];
  float acc0 = b2[f];
  float acc1 = 0.f;
  int i = beg;
  for (; i + 1 < end; i += 2) {
    int2 e0 = epk[i], e1 = epk[i + 1];
    acc0 += H2[e0.x * C_F + f] * __int_as_float(e0.y);
    acc1 += H2[e1.x * C_F + f] * __int_as_float(e1.y);
  }
  if (i < end) {
    int2 e0 = epk[i];
    acc0 += H2[e0.x * C_F + f] * __int_as_float(e0.y);
  }
  out[n * C_F + f] = acc0 + acc1;
}

extern "C" void kernel_launch(void* const* d_in, const int* in_sizes, int n_in,
                              void* d_out, int out_size, void* d_ws,
                              size_t ws_size, hipStream_t stream) {
  const float* X  = (const float*)d_in[0];
  const float* ew = (const float*)d_in[1];
  const float* W1 = (const float*)d_in[2];
  const float* b1 = (const float*)d_in[3];
  const float* W2 = (const float*)d_in[4];
  const float* b2 = (const float*)d_in[5];
  const int* src  = (const int*)d_in[6];
  const int* dst  = (const int*)d_in[7];
  float* out = (float*)d_out;

  float* H1   = (float*)d_ws;                         // 25.6 MB, reused as H2
  float* agg1 = H1 + (size_t)N_NODES * H_F;           // 25.6 MB
  int2* epk   = (int2*)(agg1 + (size_t)N_NODES * H_F); // 12.8 MB packed edges
  int* offs   = (int*)(epk + N_EDGES);                // 100001 i
  int* deg    = offs + (N_NODES + 32);                // 100K i (reused cursor)
  int* cursor = deg;
  int* blockSums = deg + N_NODES;
  int* blockOffs = blockSums + 512;
  float* H2 = H1;

  const int nbN = (N_NODES + 255) / 256;  // 391
  const int nbE = (N_EDGES + 255) / 256;  // 6250

  // CSR build (dst-keyed; shared by both layers)
  zero_deg_kernel<<<nbN, 256, 0, stream>>>(deg);
  hist_kernel<<<nbE, 256, 0, stream>>>(dst, deg);
  scan_a_kernel<<<SCAN_NB, 256, 0, stream>>>(deg, offs, blockSums);
  scan_b_kernel<<<1, 512, 0, stream>>>(blockSums, blockOffs, offs);
  scan_c_kernel<<<SCAN_NB, 256, 0, stream>>>(offs, blockOffs, cursor);
  fill_kernel<<<nbE, 256, 0, stream>>>(src, dst, ew, cursor, epk);

  // Layer 1
  gemm1_mfma_kernel<<<(N_NODES / 16 + 3) / 4, 256, 0, stream>>>(X, W1, H1);
  gather1_kernel<<<(N_NODES * 64 + 255) / 256, 256, 0, stream>>>(
      H1, offs, epk, b1, agg1);
  // Layer 2
  gemm2_kernel<<<(N_NODES * C_F + 255) / 256, 256, 0, stream>>>(agg1, W2, H2);
  gather2_kernel<<<(N_NODES * C_F + 255) / 256, 256, 0, stream>>>(
      H2, offs, epk, b2, out);
}